// Round 4
// baseline (10484.966 us; speedup 1.0000x reference)
//
#include <hip/hip_runtime.h>
#include <math.h>

#define NNEI 120
#define EMB 128
#define ROWS_PER_WAVE 15   // 8 waves * 15 = 120 rows
#define XS_STRIDE 128      // xs read uniform-broadcast or lane-consecutive -> no conflicts
#define KS_STRIDE 129      // +1 pad: (lane*129+h)%32 = (lane+h)%32 -> 2-way alias (free)
#define SCALING 0.08838834764831845f
#define SHIFT 20.0f

__device__ __forceinline__ float wsum(float v) {
#pragma unroll
    for (int off = 32; off > 0; off >>= 1) v += __shfl_xor(v, off, 64);
    return v;
}
__device__ __forceinline__ float wmaxr(float v) {
#pragma unroll
    for (int off = 32; off > 0; off >>= 1) v = fmaxf(v, __shfl_xor(v, off, 64));
    return v;
}
__device__ __forceinline__ float rdlane(float v, int l) {
    return __uint_as_float(__builtin_amdgcn_readlane(__float_as_uint(v), l));
}

// One projection (two output columns: lane, lane+64) for this wave's 15 rows.
// w points at (w_in + layer_off + col_off + lane). Weights come from L2
// (shared by all 8192 blocks); one-iteration register prefetch hides the
// ~200cy L2 latency under the 120-FMA body.
__device__ __forceinline__ void proj_pass(const float* __restrict__ w,
                                          const float* xsrow,  // xs + r0*XS_STRIDE (LDS)
                                          float* a0, float* a1) {
#pragma unroll
    for (int i = 0; i < ROWS_PER_WAVE; ++i) { a0[i] = 0.f; a1[i] = 0.f; }
    float w0[4], w1[4];
#pragma unroll
    for (int j = 0; j < 4; ++j) { w0[j] = w[j * 384]; w1[j] = w[j * 384 + 64]; }
    for (int e4 = 0; e4 < 32; ++e4) {
        const int e = e4 * 4;
        float nw0[4], nw1[4];
        if (e4 < 31) {
#pragma unroll
            for (int j = 0; j < 4; ++j) {
                nw0[j] = w[(e + 4 + j) * 384];
                nw1[j] = w[(e + 4 + j) * 384 + 64];
            }
        }
#pragma unroll
        for (int i = 0; i < ROWS_PER_WAVE; ++i) {
            const float4 xv = *(const float4*)(xsrow + i * XS_STRIDE + e);
            a0[i] = fmaf(xv.x, w0[0], a0[i]);
            a0[i] = fmaf(xv.y, w0[1], a0[i]);
            a0[i] = fmaf(xv.z, w0[2], a0[i]);
            a0[i] = fmaf(xv.w, w0[3], a0[i]);
            a1[i] = fmaf(xv.x, w1[0], a1[i]);
            a1[i] = fmaf(xv.y, w1[1], a1[i]);
            a1[i] = fmaf(xv.z, w1[2], a1[i]);
            a1[i] = fmaf(xv.w, w1[3], a1[i]);
        }
        if (e4 < 31) {
#pragma unroll
            for (int j = 0; j < 4; ++j) { w0[j] = nw0[j]; w1[j] = nw1[j]; }
        }
    }
}

__launch_bounds__(512, 2)
__global__ void nga_kernel(const float* __restrict__ x,
                           const int* __restrict__ nei_mask,   // bool staged as int32
                           const float* __restrict__ input_r,
                           const float* __restrict__ sw,
                           const float* __restrict__ w_in,
                           const float* __restrict__ b_in,
                           const float* __restrict__ w_out,
                           const float* __restrict__ b_out,
                           const float* __restrict__ ln_g,
                           const float* __restrict__ ln_b,
                           float* __restrict__ out) {
    // xs: x -> (V after sync#1) -> (O after sync#3) -> y (layer0 LN), stride 128
    // ks: K (stride 129, rows 120..127 zeroed) -> attn overlay (stride 128) after sync#2
    __shared__ __align__(16) float xs[NNEI * XS_STRIDE];
    __shared__ __align__(16) float ks[128 * KS_STRIDE];
    __shared__ float sws[128];
    __shared__ float rsh[384];

    const int tid = threadIdx.x;
    const int lane = tid & 63;
    const int wave = tid >> 6;
    const int r0 = wave * ROWS_PER_WAVE;
    const int b = blockIdx.x;

    float res0[ROWS_PER_WAVE], res1[ROWS_PER_WAVE];

    // ---- load x -> xs + residual regs; sw, input_r -> LDS; zero k pad rows ----
    const float* xb = x + (size_t)b * NNEI * EMB;
#pragma unroll
    for (int i = 0; i < ROWS_PER_WAVE; ++i) {
        res0[i] = xb[(r0 + i) * EMB + lane];
        res1[i] = xb[(r0 + i) * EMB + 64 + lane];
        xs[(r0 + i) * XS_STRIDE + lane] = res0[i];
        xs[(r0 + i) * XS_STRIDE + 64 + lane] = res1[i];
    }
    if (tid < NNEI) sws[tid] = sw[(size_t)b * NNEI + tid];
    else if (tid < 128) sws[tid] = 0.f;
    for (int t = tid; t < 384; t += 512) rsh[t] = (t < 360) ? input_r[(size_t)b * 360 + t] : 0.f;
    for (int t = tid; t < 8 * KS_STRIDE; t += 512) ks[120 * KS_STRIDE + t] = 0.f;
    __syncthreads();

    // per-lane column constants (m = lane and m = lane+64; zero-padded past 120)
    const float swm0 = sws[lane];
    const float swm1 = sws[lane + 64];
    const float rm0x = rsh[lane * 3 + 0], rm0y = rsh[lane * 3 + 1], rm0z = rsh[lane * 3 + 2];
    const float rm1x = rsh[(lane + 64) * 3 + 0], rm1y = rsh[(lane + 64) * 3 + 1], rm1z = rsh[(lane + 64) * 3 + 2];

    float mrow[ROWS_PER_WAVE];
#pragma unroll
    for (int i = 0; i < ROWS_PER_WAVE; ++i)
        mrow[i] = nei_mask[(size_t)b * NNEI + r0 + i] ? 1.f : 0.f;

    for (int l = 0; l < 2; ++l) {
        const float* wi = w_in + (size_t)l * EMB * 384;
        const float* bi = b_in + (size_t)l * 384;
        const float* wo = w_out + (size_t)l * 128 * EMB;
        const float* bop = b_out + (size_t)l * EMB;
        const float* lng = ln_g + (size_t)l * EMB;
        const float* lnb = ln_b + (size_t)l * EMB;

        float a0[ROWS_PER_WAVE], a1[ROWS_PER_WAVE];
        float Q0[ROWS_PER_WAVE], Q1[ROWS_PER_WAVE];
        float V0[ROWS_PER_WAVE], V1[ROWS_PER_WAVE];

        // ---- K projection -> ks (LDS) ----
        proj_pass(wi + 128 + lane, xs + r0 * XS_STRIDE, a0, a1);
        {
            const float bk0 = bi[128 + lane], bk1 = bi[128 + 64 + lane];
#pragma unroll
            for (int i = 0; i < ROWS_PER_WAVE; ++i) {
                float t0 = a0[i] + bk0, t1 = a1[i] + bk1;
                float ss = wsum(t0 * t0 + t1 * t1);
                float sc = 1.f / fmaxf(sqrtf(ss), 1e-12f);
                ks[(r0 + i) * KS_STRIDE + lane] = t0 * sc;
                ks[(r0 + i) * KS_STRIDE + 64 + lane] = t1 * sc;
            }
        }
        // ---- Q projection -> regs ----
        proj_pass(wi + 0 + lane, xs + r0 * XS_STRIDE, a0, a1);
        {
            const float bq0 = bi[lane], bq1 = bi[64 + lane];
#pragma unroll
            for (int i = 0; i < ROWS_PER_WAVE; ++i) {
                float t0 = a0[i] + bq0, t1 = a1[i] + bq1;
                float ss = wsum(t0 * t0 + t1 * t1);
                float sc = SCALING / fmaxf(sqrtf(ss), 1e-12f);
                Q0[i] = t0 * sc; Q1[i] = t1 * sc;
            }
        }
        // ---- V projection -> regs ----
        proj_pass(wi + 256 + lane, xs + r0 * XS_STRIDE, a0, a1);
        {
            const float bv0 = bi[256 + lane], bv1 = bi[256 + 64 + lane];
#pragma unroll
            for (int i = 0; i < ROWS_PER_WAVE; ++i) {
                float t0 = a0[i] + bv0, t1 = a1[i] + bv1;
                float ss = wsum(t0 * t0 + t1 * t1);
                float sc = 1.f / fmaxf(sqrtf(ss), 1e-12f);
                V0[i] = t0 * sc; V1[i] = t1 * sc;
            }
        }
        __syncthreads();  // #1: all xs(x) reads + ks writes complete

        // ---- write v over xs (x preserved in res regs) ----
#pragma unroll
        for (int i = 0; i < ROWS_PER_WAVE; ++i) {
            xs[(r0 + i) * XS_STRIDE + lane] = V0[i];
            xs[(r0 + i) * XS_STRIDE + 64 + lane] = V1[i];
        }

        // ---- logits: S[i][m] for m=lane, lane+64 (reads ks cross-wave) ----
        float S0[ROWS_PER_WAVE], S1[ROWS_PER_WAVE];
#pragma unroll
        for (int i = 0; i < ROWS_PER_WAVE; ++i) { S0[i] = 0.f; S1[i] = 0.f; }
        for (int h = 0; h < 64; ++h) {
            float k0 = ks[lane * KS_STRIDE + h];
            float k1 = ks[(lane + 64) * KS_STRIDE + h];
#pragma unroll
            for (int i = 0; i < ROWS_PER_WAVE; ++i) {
                float qh = rdlane(Q0[i], h);
                S0[i] = fmaf(qh, k0, S0[i]);
                S1[i] = fmaf(qh, k1, S1[i]);
            }
        }
        for (int h = 0; h < 64; ++h) {
            float k0 = ks[lane * KS_STRIDE + 64 + h];
            float k1 = ks[(lane + 64) * KS_STRIDE + 64 + h];
#pragma unroll
            for (int i = 0; i < ROWS_PER_WAVE; ++i) {
                float qh = rdlane(Q1[i], h);
                S0[i] = fmaf(qh, k0, S0[i]);
                S1[i] = fmaf(qh, k1, S1[i]);
            }
        }

        // ---- softmax + smooth reweighting + mask + sw_o + angular gate ----
#pragma unroll
        for (int i = 0; i < ROWS_PER_WAVE; ++i) {
            const float swn = sws[r0 + i];
            const float g0 = swn * swm0, g1 = swn * swm1;
            float s0 = (S0[i] + SHIFT) * g0 - SHIFT;
            float s1 = (S1[i] + SHIFT) * g1 - SHIFT;
            float mx = fmaxf(s0, (lane < 56) ? s1 : -1e30f);
            mx = wmaxr(mx);
            float e0 = __expf(s0 - mx);
            float e1 = (lane < 56) ? __expf(s1 - mx) : 0.f;
            float denom = wsum(e0 + e1);
            float inv = 1.f / denom;
            const float rnx = rsh[(r0 + i) * 3 + 0];
            const float rny = rsh[(r0 + i) * 3 + 1];
            const float rnz = rsh[(r0 + i) * 3 + 2];
            float ang0 = rnx * rm0x + rny * rm0y + rnz * rm0z;
            float ang1 = rnx * rm1x + rny * rm1y + rnz * rm1z;
            S0[i] = e0 * inv * mrow[i] * g0 * ang0;   // a[i][lane]
            S1[i] = e1 * inv * mrow[i] * g1 * ang1;   // a[i][lane+64] (0 for lane>=56)
        }
        __syncthreads();  // #2: ks(K) reads + xs(v) writes complete

        // ---- attn -> LDS overlay over ks (own rows; stride 128) ----
        float* alds = ks;  // reuse dead K storage
#pragma unroll
        for (int i = 0; i < ROWS_PER_WAVE; ++i) {
            alds[(r0 + i) * 128 + lane] = S0[i];
            alds[(r0 + i) * 128 + 64 + lane] = S1[i];
        }
        // (own-row RAW only: no barrier needed before PV reads below)

        // ---- PV: o = attn @ v (a uniform b128 quads, v lane-indexed) ----
        float O0[ROWS_PER_WAVE], O1[ROWS_PER_WAVE];
#pragma unroll
        for (int i = 0; i < ROWS_PER_WAVE; ++i) { O0[i] = 0.f; O1[i] = 0.f; }
        for (int mq = 0; mq < 30; ++mq) {
            const int m = mq * 4;
            float v0[4], v1[4];
#pragma unroll
            for (int j = 0; j < 4; ++j) {
                v0[j] = xs[(m + j) * XS_STRIDE + lane];
                v1[j] = xs[(m + j) * XS_STRIDE + 64 + lane];
            }
#pragma unroll
            for (int i = 0; i < ROWS_PER_WAVE; ++i) {
                const float4 aq = *(const float4*)(alds + (r0 + i) * 128 + m);
                O0[i] = fmaf(aq.x, v0[0], O0[i]);
                O0[i] = fmaf(aq.y, v0[1], O0[i]);
                O0[i] = fmaf(aq.z, v0[2], O0[i]);
                O0[i] = fmaf(aq.w, v0[3], O0[i]);
                O1[i] = fmaf(aq.x, v1[0], O1[i]);
                O1[i] = fmaf(aq.y, v1[1], O1[i]);
                O1[i] = fmaf(aq.z, v1[2], O1[i]);
                O1[i] = fmaf(aq.w, v1[3], O1[i]);
            }
        }
        __syncthreads();  // #3: all xs(v) reads done (xs reusable for O)

        // ---- O -> LDS overlay over xs (own rows) ----
#pragma unroll
        for (int i = 0; i < ROWS_PER_WAVE; ++i) {
            xs[(r0 + i) * XS_STRIDE + lane] = O0[i];
            xs[(r0 + i) * XS_STRIDE + 64 + lane] = O1[i];
        }

        // ---- out_proj + bias (O uniform b128 quads, w coalesced from L2) ----
        float U0[ROWS_PER_WAVE], U1[ROWS_PER_WAVE];
        {
            const float bo0 = bop[lane], bo1 = bop[64 + lane];
#pragma unroll
            for (int i = 0; i < ROWS_PER_WAVE; ++i) { U0[i] = bo0; U1[i] = bo1; }
        }
        for (int hq = 0; hq < 32; ++hq) {
            const int h = hq * 4;
            float w0[4], w1[4];
#pragma unroll
            for (int j = 0; j < 4; ++j) {
                w0[j] = wo[(h + j) * 128 + lane];
                w1[j] = wo[(h + j) * 128 + 64 + lane];
            }
#pragma unroll
            for (int i = 0; i < ROWS_PER_WAVE; ++i) {
                const float4 oq = *(const float4*)(xs + (r0 + i) * XS_STRIDE + h);
                U0[i] = fmaf(oq.x, w0[0], U0[i]);
                U0[i] = fmaf(oq.y, w0[1], U0[i]);
                U0[i] = fmaf(oq.z, w0[2], U0[i]);
                U0[i] = fmaf(oq.w, w0[3], U0[i]);
                U1[i] = fmaf(oq.x, w1[0], U1[i]);
                U1[i] = fmaf(oq.y, w1[1], U1[i]);
                U1[i] = fmaf(oq.z, w1[2], U1[i]);
                U1[i] = fmaf(oq.w, w1[3], U1[i]);
            }
        }

        // ---- residual + LayerNorm; write new x over xs (layer 0) or output ----
        {
            const float gg0 = lng[lane], gg1 = lng[64 + lane];
            const float bb0 = lnb[lane], bb1 = lnb[64 + lane];
            float* outp = out + (size_t)b * NNEI * EMB;
#pragma unroll
            for (int i = 0; i < ROWS_PER_WAVE; ++i) {
                float t0 = res0[i] + U0[i];
                float t1 = res1[i] + U1[i];
                float s = wsum(t0 + t1);
                float s2 = wsum(t0 * t0 + t1 * t1);
                float mu = s * (1.f / 128.f);
                float var = s2 * (1.f / 128.f) - mu * mu;
                float rstd = rsqrtf(var + 1e-5f);
                float y0 = (t0 - mu) * rstd * gg0 + bb0;
                float y1 = (t1 - mu) * rstd * gg1 + bb1;
                if (l == 0) {
                    xs[(r0 + i) * XS_STRIDE + lane] = y0;
                    xs[(r0 + i) * XS_STRIDE + 64 + lane] = y1;
                    res0[i] = y0; res1[i] = y1;
                } else {
                    outp[(r0 + i) * EMB + lane] = y0;
                    outp[(r0 + i) * EMB + 64 + lane] = y1;
                }
            }
        }
        __syncthreads();  // #4: guards a-overlay (stride 128) vs next-layer K writes (stride 129)
    }
}

extern "C" void kernel_launch(void* const* d_in, const int* in_sizes, int n_in,
                              void* d_out, int out_size, void* d_ws, size_t ws_size,
                              hipStream_t stream) {
    const float* x = (const float*)d_in[0];
    const int* nei_mask = (const int*)d_in[1];   // bool -> int32 per harness staging
    const float* input_r = (const float*)d_in[2];
    const float* sw = (const float*)d_in[3];
    const float* w_in = (const float*)d_in[4];
    const float* b_in = (const float*)d_in[5];
    const float* w_out = (const float*)d_in[6];
    const float* b_out = (const float*)d_in[7];
    const float* ln_g = (const float*)d_in[8];
    const float* ln_b = (const float*)d_in[9];
    float* out = (float*)d_out;

    const int B = in_sizes[0] / (NNEI * EMB);
    nga_kernel<<<B, 512, 0, stream>>>(x, nei_mask, input_r, sw, w_in, b_in,
                                      w_out, b_out, ln_g, ln_b, out);
}